// Round 1
// baseline (216.257 us; speedup 1.0000x reference)
//
#include <hip/hip_runtime.h>
#include <math.h>

// TD(lambda) backward scan as a parallel suffix scan of affine maps.
// ret[t] = b[t] + a[t]*ret[t+1],  a[t]=g*(1-d)*lam[t],  b[t]=r[t]+g*(1-d)*(1-lam[t])*v[t+1]
// One block per batch row; thread owns C=8 contiguous timesteps.

#define EPSV 1e-8f

__global__ void precompute_lambda_kernel(const float* __restrict__ raw_gamma,
                                         const float* __restrict__ raw_lambd,
                                         float* __restrict__ lam, int S) {
    int t = blockIdx.x * blockDim.x + threadIdx.x;
    if (t < S) lam[t] = fmaxf(tanhf(raw_lambd[t]), EPSV);
    if (t == S) lam[S] = fmaxf(tanhf(raw_gamma[0]), EPSV);  // gamma stashed at lam[S]
}

__global__ __launch_bounds__(256) void lamret_kernel(
    const float* __restrict__ values,    // [B, S+1]
    const float* __restrict__ rewards,   // [B, S]
    const float* __restrict__ dones,     // [B, S]
    const float* __restrict__ raw_gamma, // [1]   (fallback path)
    const float* __restrict__ raw_lambd, // [S]   (fallback path)
    const float* __restrict__ lam_pre,   // [S+1] precomputed (or nullptr)
    float* __restrict__ out,             // [B, S]
    int S)
{
    constexpr int C = 8;
    const int row  = blockIdx.x;
    const int tid  = threadIdx.x;
    const int lane = tid & 63;
    const int wave = tid >> 6;
    const int nwaves = blockDim.x >> 6;
    const int t0 = tid * C;

    const float* __restrict__ rrow = rewards + (size_t)row * S;
    const float* __restrict__ drow = dones   + (size_t)row * S;
    const float* __restrict__ vrow = values  + (size_t)row * (S + 1);

    float gamma;
    if (lam_pre) gamma = lam_pre[S];
    else         gamma = fmaxf(tanhf(raw_gamma[0]), EPSV);

    float a[C], b[C];
    const bool full = (t0 + C <= S);
    if (full) {
        // vectorized loads: rrow+t0 / drow+t0 are 32B-aligned
        const float4* r4 = reinterpret_cast<const float4*>(rrow + t0);
        const float4* d4 = reinterpret_cast<const float4*>(drow + t0);
        float4 r01 = r4[0], r23 = r4[1];
        float4 d01 = d4[0], d23 = d4[1];
        float rr[C] = {r01.x, r01.y, r01.z, r01.w, r23.x, r23.y, r23.z, r23.w};
        float dd[C] = {d01.x, d01.y, d01.z, d01.w, d23.x, d23.y, d23.z, d23.w};
        float lm[C];
        if (lam_pre) {
            const float4* l4 = reinterpret_cast<const float4*>(lam_pre + t0);
            float4 l01 = l4[0], l23 = l4[1];
            lm[0]=l01.x; lm[1]=l01.y; lm[2]=l01.z; lm[3]=l01.w;
            lm[4]=l23.x; lm[5]=l23.y; lm[6]=l23.z; lm[7]=l23.w;
        } else {
            #pragma unroll
            for (int i = 0; i < C; ++i) lm[i] = fmaxf(tanhf(raw_lambd[t0 + i]), EPSV);
        }
        float vv[C];
        #pragma unroll
        for (int i = 0; i < C; ++i) vv[i] = vrow[t0 + 1 + i];  // odd row stride: scalar
        #pragma unroll
        for (int i = 0; i < C; ++i) {
            float g1d = gamma * (1.0f - dd[i]);
            a[i] = g1d * lm[i];
            b[i] = rr[i] + g1d * (1.0f - lm[i]) * vv[i];
        }
    } else {
        #pragma unroll
        for (int i = 0; i < C; ++i) {
            int t = t0 + i;
            if (t < S) {
                float lmv = lam_pre ? lam_pre[t] : fmaxf(tanhf(raw_lambd[t]), EPSV);
                float g1d = gamma * (1.0f - drow[t]);
                a[i] = g1d * lmv;
                b[i] = rrow[t] + g1d * (1.0f - lmv) * vrow[t + 1];
            } else { a[i] = 1.0f; b[i] = 0.0f; }
        }
    }

    // local composition H_tid = f_{t0} o ... o f_{t0+C-1}
    float A = 1.0f, Bc = 0.0f;
    #pragma unroll
    for (int i = C - 1; i >= 0; --i) {
        Bc = fmaf(a[i], Bc, b[i]);
        A  = a[i] * A;
    }

    // wave-level inclusive suffix scan (composition; lane j covers lanes j..63)
    float Ai = A, Bi = Bc;
    #pragma unroll
    for (int off = 1; off < 64; off <<= 1) {
        float Ao = __shfl_down(Ai, off);
        float Bo = __shfl_down(Bi, off);
        if (lane + off < 64) {
            Bi = fmaf(Ai, Bo, Bi);
            Ai = Ai * Ao;
        }
    }
    // exclusive within wave (lanes lane+1..63); lane 63 = identity
    float Ae = __shfl_down(Ai, 1);
    float Be = __shfl_down(Bi, 1);
    if (lane == 63) { Ae = 1.0f; Be = 0.0f; }

    // cross-wave combine: aggregate of wave w = lane 0's inclusive result
    __shared__ float aggA[8], aggB[8];
    if (lane == 0) { aggA[wave] = Ai; aggB[wave] = Bi; }
    __syncthreads();
    float TA = 1.0f, TB = 0.0f;           // tail = agg[w+1] o ... o agg[nw-1]
    for (int w2 = wave + 1; w2 < nwaves; ++w2) {
        TB = fmaf(TA, aggB[w2], TB);
        TA = TA * aggA[w2];
    }
    // full exclusive carry map E = excl_wave o tail
    float Af = Ae * TA;
    float Bf = fmaf(Ae, TB, Be);

    const float vlast = vrow[S];
    float x = fmaf(Af, vlast, Bf);        // carry entering this thread's chunk

    // backward apply within chunk
    float o[C];
    #pragma unroll
    for (int i = C - 1; i >= 0; --i) {
        x = fmaf(a[i], x, b[i]);
        o[i] = x;
    }

    float* __restrict__ orow = out + (size_t)row * S;
    if (full) {
        float4* o4 = reinterpret_cast<float4*>(orow + t0);
        o4[0] = make_float4(o[0], o[1], o[2], o[3]);
        o4[1] = make_float4(o[4], o[5], o[6], o[7]);
    } else {
        for (int i = 0; i < C; ++i)
            if (t0 + i < S) orow[t0 + i] = o[i];
    }
}

extern "C" void kernel_launch(void* const* d_in, const int* in_sizes, int n_in,
                              void* d_out, int out_size, void* d_ws, size_t ws_size,
                              hipStream_t stream) {
    const float* values    = (const float*)d_in[0];
    const float* rewards   = (const float*)d_in[1];
    const float* dones     = (const float*)d_in[2];
    const float* raw_gamma = (const float*)d_in[3];
    const float* raw_lambd = (const float*)d_in[4];
    float* out = (float*)d_out;

    const int S = in_sizes[4];            // raw_lambd length
    const int B = in_sizes[1] / S;        // rewards = B*S

    float* lam_pre = nullptr;
    if (ws_size >= (size_t)(S + 1) * sizeof(float)) {
        lam_pre = (float*)d_ws;
        int nthr = 256;
        int nblk = (S + 1 + nthr - 1) / nthr;
        precompute_lambda_kernel<<<nblk, nthr, 0, stream>>>(raw_gamma, raw_lambd, lam_pre, S);
    }

    // one block per row; 256 threads * 8 steps = 2048 timesteps per block
    lamret_kernel<<<B, 256, 0, stream>>>(values, rewards, dones,
                                         raw_gamma, raw_lambd, lam_pre, out, S);
}

// Round 3
// 215.225 us; speedup vs baseline: 1.0048x; 1.0048x over previous
//
#include <hip/hip_runtime.h>
#include <math.h>

// TD(lambda) backward scan as a parallel suffix scan of affine maps.
// ret[t] = b[t] + a[t]*ret[t+1],  a[t]=g*(1-d)*lam[t],  b[t]=r[t]+g*(1-d)*(1-lam[t])*v[t+1]
// One block per batch row; thread owns C=8 contiguous timesteps.
//
// R2b: values staged through LDS with coalesced dword loads + padded layout
// (f(t)=t+(t>>3): global loads 100% line-utilized, LDS chunk reads 2-way
// bank aliasing = free). Nontemporal hints on streamed r/d/v loads and out
// stores. Uses clang ext_vector f32x4 (HIP float4 is a class type and is
// rejected by __builtin_nontemporal_*).

#define EPSV 1e-8f
#define MAX_S 2048
#define LDSF(t) ((t) + ((t) >> 3))

typedef float f32x4 __attribute__((ext_vector_type(4)));

__global__ void precompute_lambda_kernel(const float* __restrict__ raw_gamma,
                                         const float* __restrict__ raw_lambd,
                                         float* __restrict__ lam, int S) {
    int t = blockIdx.x * blockDim.x + threadIdx.x;
    if (t < S) lam[t] = fmaxf(tanhf(raw_lambd[t]), EPSV);
    if (t == S) lam[S] = fmaxf(tanhf(raw_gamma[0]), EPSV);  // gamma stashed at lam[S]
}

__global__ __launch_bounds__(256) void lamret_kernel(
    const float* __restrict__ values,    // [B, S+1]
    const float* __restrict__ rewards,   // [B, S]
    const float* __restrict__ dones,     // [B, S]
    const float* __restrict__ raw_gamma, // [1]   (fallback path)
    const float* __restrict__ raw_lambd, // [S]   (fallback path)
    const float* __restrict__ lam_pre,   // [S+1] precomputed (or nullptr)
    float* __restrict__ out,             // [B, S]
    int S)
{
    constexpr int C = 8;
    __shared__ float vbuf[LDSF(MAX_S) + 2];  // padded: ~9.2KB
    __shared__ float aggA[4], aggB[4];

    const int row  = blockIdx.x;
    const int tid  = threadIdx.x;
    const int lane = tid & 63;
    const int wave = tid >> 6;
    const int nwaves = 4;  // 256 threads
    const int t0 = tid * C;

    const float* __restrict__ rrow = rewards + (size_t)row * S;
    const float* __restrict__ drow = dones   + (size_t)row * S;
    const float* __restrict__ vrow = values  + (size_t)row * (S + 1);

    const bool use_lds = (S <= MAX_S);
    if (use_lds) {
        // coalesced lane-contiguous dword loads of the whole values row
        for (int t = tid; t <= S; t += 256)
            vbuf[LDSF(t)] = __builtin_nontemporal_load(vrow + t);
    }

    float gamma;
    if (lam_pre) gamma = lam_pre[S];
    else         gamma = fmaxf(tanhf(raw_gamma[0]), EPSV);

    float a[C], b[C];
    const bool full = (t0 + C <= S) && ((S & 3) == 0);
    float rr[C], dd[C], lm[C];
    if (full) {
        // rrow/drow + t0 are 16B-aligned (S multiple of 4, t0 multiple of 8)
        const f32x4* r4 = reinterpret_cast<const f32x4*>(rrow + t0);
        const f32x4* d4 = reinterpret_cast<const f32x4*>(drow + t0);
        f32x4 r01 = __builtin_nontemporal_load(r4);
        f32x4 r23 = __builtin_nontemporal_load(r4 + 1);
        f32x4 d01 = __builtin_nontemporal_load(d4);
        f32x4 d23 = __builtin_nontemporal_load(d4 + 1);
        #pragma unroll
        for (int i = 0; i < 4; ++i) { rr[i] = r01[i]; rr[4+i] = r23[i]; }
        #pragma unroll
        for (int i = 0; i < 4; ++i) { dd[i] = d01[i]; dd[4+i] = d23[i]; }
        if (lam_pre) {
            const f32x4* l4 = reinterpret_cast<const f32x4*>(lam_pre + t0);
            f32x4 l01 = l4[0], l23 = l4[1];
            #pragma unroll
            for (int i = 0; i < 4; ++i) { lm[i] = l01[i]; lm[4+i] = l23[i]; }
        } else {
            #pragma unroll
            for (int i = 0; i < C; ++i) lm[i] = fmaxf(tanhf(raw_lambd[t0 + i]), EPSV);
        }
    }

    if (use_lds) __syncthreads();  // vbuf ready

    if (full) {
        float vv[C];
        if (use_lds) {
            #pragma unroll
            for (int i = 0; i < C; ++i) { int t = t0 + 1 + i; vv[i] = vbuf[LDSF(t)]; }
        } else {
            #pragma unroll
            for (int i = 0; i < C; ++i) vv[i] = vrow[t0 + 1 + i];
        }
        #pragma unroll
        for (int i = 0; i < C; ++i) {
            float g1d = gamma * (1.0f - dd[i]);
            a[i] = g1d * lm[i];
            b[i] = fmaf(g1d * (1.0f - lm[i]), vv[i], rr[i]);
        }
    } else {
        #pragma unroll
        for (int i = 0; i < C; ++i) {
            int t = t0 + i;
            if (t < S) {
                float lmv = lam_pre ? lam_pre[t] : fmaxf(tanhf(raw_lambd[t]), EPSV);
                float g1d = gamma * (1.0f - drow[t]);
                float vnt = use_lds ? vbuf[LDSF(t + 1)] : vrow[t + 1];
                a[i] = g1d * lmv;
                b[i] = fmaf(g1d * (1.0f - lmv), vnt, rrow[t]);
            } else { a[i] = 1.0f; b[i] = 0.0f; }
        }
    }

    // local composition H_tid = f_{t0} o ... o f_{t0+C-1}
    float A = 1.0f, Bc = 0.0f;
    #pragma unroll
    for (int i = C - 1; i >= 0; --i) {
        Bc = fmaf(a[i], Bc, b[i]);
        A  = a[i] * A;
    }

    // wave-level inclusive suffix scan (composition; lane j covers lanes j..63)
    float Ai = A, Bi = Bc;
    #pragma unroll
    for (int off = 1; off < 64; off <<= 1) {
        float Ao = __shfl_down(Ai, off);
        float Bo = __shfl_down(Bi, off);
        if (lane + off < 64) {
            Bi = fmaf(Ai, Bo, Bi);
            Ai = Ai * Ao;
        }
    }
    // exclusive within wave (lanes lane+1..63); lane 63 = identity
    float Ae = __shfl_down(Ai, 1);
    float Be = __shfl_down(Bi, 1);
    if (lane == 63) { Ae = 1.0f; Be = 0.0f; }

    // cross-wave combine: aggregate of wave w = lane 0's inclusive result
    if (lane == 0) { aggA[wave] = Ai; aggB[wave] = Bi; }
    __syncthreads();
    float TA = 1.0f, TB = 0.0f;           // tail = agg[w+1] o ... o agg[nw-1]
    for (int w2 = wave + 1; w2 < nwaves; ++w2) {
        TB = fmaf(TA, aggB[w2], TB);
        TA = TA * aggA[w2];
    }
    // full exclusive carry map E = excl_wave o tail
    float Af = Ae * TA;
    float Bf = fmaf(Ae, TB, Be);

    const float vlast = use_lds ? vbuf[LDSF(S)] : vrow[S];
    float x = fmaf(Af, vlast, Bf);        // carry entering this thread's chunk

    // backward apply within chunk
    float o[C];
    #pragma unroll
    for (int i = C - 1; i >= 0; --i) {
        x = fmaf(a[i], x, b[i]);
        o[i] = x;
    }

    float* __restrict__ orow = out + (size_t)row * S;
    if (full) {
        f32x4* o4 = reinterpret_cast<f32x4*>(orow + t0);
        f32x4 o01, o23;
        #pragma unroll
        for (int i = 0; i < 4; ++i) { o01[i] = o[i]; o23[i] = o[4+i]; }
        __builtin_nontemporal_store(o01, o4);
        __builtin_nontemporal_store(o23, o4 + 1);
    } else {
        for (int i = 0; i < C; ++i)
            if (t0 + i < S) orow[t0 + i] = o[i];
    }
}

extern "C" void kernel_launch(void* const* d_in, const int* in_sizes, int n_in,
                              void* d_out, int out_size, void* d_ws, size_t ws_size,
                              hipStream_t stream) {
    const float* values    = (const float*)d_in[0];
    const float* rewards   = (const float*)d_in[1];
    const float* dones     = (const float*)d_in[2];
    const float* raw_gamma = (const float*)d_in[3];
    const float* raw_lambd = (const float*)d_in[4];
    float* out = (float*)d_out;

    const int S = in_sizes[4];            // raw_lambd length
    const int B = in_sizes[1] / S;        // rewards = B*S

    float* lam_pre = nullptr;
    if (ws_size >= (size_t)(S + 1) * sizeof(float)) {
        lam_pre = (float*)d_ws;
        int nthr = 256;
        int nblk = (S + 1 + nthr - 1) / nthr;
        precompute_lambda_kernel<<<nblk, nthr, 0, stream>>>(raw_gamma, raw_lambd, lam_pre, S);
    }

    // one block per row; 256 threads * 8 steps = 2048 timesteps per block
    lamret_kernel<<<B, 256, 0, stream>>>(values, rewards, dones,
                                         raw_gamma, raw_lambd, lam_pre, out, S);
}

// Round 4
// 209.299 us; speedup vs baseline: 1.0332x; 1.0283x over previous
//
#include <hip/hip_runtime.h>
#include <math.h>

// TD(lambda) backward scan as a parallel suffix scan of affine maps.
// ret[t] = b[t] + a[t]*ret[t+1],  a[t]=g*(1-d)*lam[t],  b[t]=r[t]+g*(1-d)*(1-lam[t])*v[t+1]
// One block per batch row; thread owns C=8 contiguous timesteps.
//
// R4: values LDS staging removed. vrow+t0+1 misalignment is wave-uniform
// (stride S+1 === 1 mod 4, t0 === 0 mod 8), so each thread loads an aligned
// 12-float window (3x dwordx4) and selects its 8 via a uniform 4-way branch.
// No first __syncthreads, no vmcnt(0) drain before compute, no LDS traffic
// except the 4-wide cross-wave aggregate.

#define EPSV 1e-8f

typedef float f32x4 __attribute__((ext_vector_type(4)));

__global__ void precompute_lambda_kernel(const float* __restrict__ raw_gamma,
                                         const float* __restrict__ raw_lambd,
                                         float* __restrict__ lam, int S) {
    int t = blockIdx.x * blockDim.x + threadIdx.x;
    if (t < S) lam[t] = fmaxf(tanhf(raw_lambd[t]), EPSV);
    if (t == S) lam[S] = fmaxf(tanhf(raw_gamma[0]), EPSV);  // gamma stashed at lam[S]
}

__global__ __launch_bounds__(256) void lamret_kernel(
    const float* __restrict__ values,    // [B, S+1]
    const float* __restrict__ rewards,   // [B, S]
    const float* __restrict__ dones,     // [B, S]
    const float* __restrict__ raw_gamma, // [1]   (fallback path)
    const float* __restrict__ raw_lambd, // [S]   (fallback path)
    const float* __restrict__ lam_pre,   // [S+1] precomputed (or nullptr)
    float* __restrict__ out,             // [B, S]
    int S, long vtotal)
{
    constexpr int C = 8;
    __shared__ float aggA[4], aggB[4];

    const int row  = blockIdx.x;
    const int tid  = threadIdx.x;
    const int lane = tid & 63;
    const int wave = tid >> 6;
    const int nwaves = 4;  // 256 threads
    const int t0 = tid * C;

    const float* __restrict__ rrow = rewards + (size_t)row * S;
    const float* __restrict__ drow = dones   + (size_t)row * S;
    const float* __restrict__ vrow = values  + (size_t)row * (S + 1);

    float gamma;
    if (lam_pre) gamma = lam_pre[S];
    else         gamma = fmaxf(tanhf(raw_gamma[0]), EPSV);

    float a[C], b[C];
    const bool full = (t0 + C <= S) && ((S & 3) == 0);
    if (full) {
        // ---- issue all global loads up front, no barrier in between ----
        const f32x4* r4 = reinterpret_cast<const f32x4*>(rrow + t0);
        const f32x4* d4 = reinterpret_cast<const f32x4*>(drow + t0);
        f32x4 r01 = __builtin_nontemporal_load(r4);
        f32x4 r23 = __builtin_nontemporal_load(r4 + 1);
        f32x4 d01 = __builtin_nontemporal_load(d4);
        f32x4 d23 = __builtin_nontemporal_load(d4 + 1);

        // values window: aligned 16B loads + wave-uniform select
        const float* vp = vrow + t0 + 1;
        const int ofs = (int)(((uintptr_t)vp >> 2) & 3);  // uniform per wave
        const float* base = vp - ofs;
        float vv[C];
        if (ofs == 0) {
            f32x4 w0 = *reinterpret_cast<const f32x4*>(base);
            f32x4 w1 = *reinterpret_cast<const f32x4*>(base + 4);
            #pragma unroll
            for (int i = 0; i < 4; ++i) { vv[i] = w0[i]; vv[4+i] = w1[i]; }
        } else if (base + 12 <= values + vtotal) {
            f32x4 w0 = *reinterpret_cast<const f32x4*>(base);
            f32x4 w1 = *reinterpret_cast<const f32x4*>(base + 4);
            f32x4 w2 = *reinterpret_cast<const f32x4*>(base + 8);
            if (ofs == 1) {
                vv[0]=w0[1]; vv[1]=w0[2]; vv[2]=w0[3];
                vv[3]=w1[0]; vv[4]=w1[1]; vv[5]=w1[2]; vv[6]=w1[3];
                vv[7]=w2[0];
            } else if (ofs == 2) {
                vv[0]=w0[2]; vv[1]=w0[3];
                vv[2]=w1[0]; vv[3]=w1[1]; vv[4]=w1[2]; vv[5]=w1[3];
                vv[6]=w2[0]; vv[7]=w2[1];
            } else {
                vv[0]=w0[3];
                vv[1]=w1[0]; vv[2]=w1[1]; vv[3]=w1[2]; vv[4]=w1[3];
                vv[5]=w2[0]; vv[6]=w2[1]; vv[7]=w2[2];
            }
        } else {
            #pragma unroll
            for (int i = 0; i < C; ++i) vv[i] = vp[i];
        }

        float lm[C];
        if (lam_pre) {
            const f32x4* l4 = reinterpret_cast<const f32x4*>(lam_pre + t0);
            f32x4 l01 = l4[0], l23 = l4[1];
            #pragma unroll
            for (int i = 0; i < 4; ++i) { lm[i] = l01[i]; lm[4+i] = l23[i]; }
        } else {
            #pragma unroll
            for (int i = 0; i < C; ++i) lm[i] = fmaxf(tanhf(raw_lambd[t0 + i]), EPSV);
        }

        float rr[C], dd[C];
        #pragma unroll
        for (int i = 0; i < 4; ++i) { rr[i] = r01[i]; rr[4+i] = r23[i]; }
        #pragma unroll
        for (int i = 0; i < 4; ++i) { dd[i] = d01[i]; dd[4+i] = d23[i]; }

        #pragma unroll
        for (int i = 0; i < C; ++i) {
            float g1d = gamma * (1.0f - dd[i]);
            a[i] = g1d * lm[i];
            b[i] = fmaf(g1d * (1.0f - lm[i]), vv[i], rr[i]);
        }
    } else {
        #pragma unroll
        for (int i = 0; i < C; ++i) {
            int t = t0 + i;
            if (t < S) {
                float lmv = lam_pre ? lam_pre[t] : fmaxf(tanhf(raw_lambd[t]), EPSV);
                float g1d = gamma * (1.0f - drow[t]);
                a[i] = g1d * lmv;
                b[i] = fmaf(g1d * (1.0f - lmv), vrow[t + 1], rrow[t]);
            } else { a[i] = 1.0f; b[i] = 0.0f; }
        }
    }

    // local composition H_tid = f_{t0} o ... o f_{t0+C-1}
    float A = 1.0f, Bc = 0.0f;
    #pragma unroll
    for (int i = C - 1; i >= 0; --i) {
        Bc = fmaf(a[i], Bc, b[i]);
        A  = a[i] * A;
    }

    // wave-level inclusive suffix scan (composition; lane j covers lanes j..63)
    float Ai = A, Bi = Bc;
    #pragma unroll
    for (int off = 1; off < 64; off <<= 1) {
        float Ao = __shfl_down(Ai, off);
        float Bo = __shfl_down(Bi, off);
        if (lane + off < 64) {
            Bi = fmaf(Ai, Bo, Bi);
            Ai = Ai * Ao;
        }
    }
    // exclusive within wave (lanes lane+1..63); lane 63 = identity
    float Ae = __shfl_down(Ai, 1);
    float Be = __shfl_down(Bi, 1);
    if (lane == 63) { Ae = 1.0f; Be = 0.0f; }

    // cross-wave combine: aggregate of wave w = lane 0's inclusive result
    if (lane == 0) { aggA[wave] = Ai; aggB[wave] = Bi; }
    __syncthreads();
    float TA = 1.0f, TB = 0.0f;           // tail = agg[w+1] o ... o agg[nw-1]
    for (int w2 = wave + 1; w2 < nwaves; ++w2) {
        TB = fmaf(TA, aggB[w2], TB);
        TA = TA * aggA[w2];
    }
    // full exclusive carry map E = excl_wave o tail
    float Af = Ae * TA;
    float Bf = fmaf(Ae, TB, Be);

    const float vlast = vrow[S];          // uniform address -> scalar load
    float x = fmaf(Af, vlast, Bf);        // carry entering this thread's chunk

    // backward apply within chunk
    float o[C];
    #pragma unroll
    for (int i = C - 1; i >= 0; --i) {
        x = fmaf(a[i], x, b[i]);
        o[i] = x;
    }

    float* __restrict__ orow = out + (size_t)row * S;
    if (full) {
        f32x4* o4 = reinterpret_cast<f32x4*>(orow + t0);
        f32x4 o01, o23;
        #pragma unroll
        for (int i = 0; i < 4; ++i) { o01[i] = o[i]; o23[i] = o[4+i]; }
        __builtin_nontemporal_store(o01, o4);
        __builtin_nontemporal_store(o23, o4 + 1);
    } else {
        for (int i = 0; i < C; ++i)
            if (t0 + i < S) orow[t0 + i] = o[i];
    }
}

extern "C" void kernel_launch(void* const* d_in, const int* in_sizes, int n_in,
                              void* d_out, int out_size, void* d_ws, size_t ws_size,
                              hipStream_t stream) {
    const float* values    = (const float*)d_in[0];
    const float* rewards   = (const float*)d_in[1];
    const float* dones     = (const float*)d_in[2];
    const float* raw_gamma = (const float*)d_in[3];
    const float* raw_lambd = (const float*)d_in[4];
    float* out = (float*)d_out;

    const int S = in_sizes[4];            // raw_lambd length
    const int B = in_sizes[1] / S;        // rewards = B*S
    const long vtotal = in_sizes[0];      // B*(S+1)

    float* lam_pre = nullptr;
    if (ws_size >= (size_t)(S + 1) * sizeof(float)) {
        lam_pre = (float*)d_ws;
        int nthr = 256;
        int nblk = (S + 1 + nthr - 1) / nthr;
        precompute_lambda_kernel<<<nblk, nthr, 0, stream>>>(raw_gamma, raw_lambd, lam_pre, S);
    }

    // one block per row; 256 threads * 8 steps = 2048 timesteps per block
    lamret_kernel<<<B, 256, 0, stream>>>(values, rewards, dones,
                                         raw_gamma, raw_lambd, lam_pre, out, S, vtotal);
}